// Round 7
// baseline (140.477 us; speedup 1.0000x reference)
//
#include <hip/hip_runtime.h>
#include <math.h>

#define SS 2048
#define BB 64
#define DD 1024

// Kernel A: v[b][d] = sum_e h[b,e] * W[e,d]
// grid (DD/64, BB/16) = (16,4) = 64 blocks, block 1024 = 16 waves (e-split 16).
// Each block: 64-wide d-stripe, 16 b's -> W stripe read ONCE per block
// (W traffic 16 MB total, 4x less than before). Thread (eg,dl): eg = e-group
// (0..15, 64 iters each), dl = d-lane. acc[16] per thread; LDS reduce over eg.
__global__ __launch_bounds__(1024) void proj_vec_kernel(
    const float* __restrict__ h, const float* __restrict__ W, float* __restrict__ v) {
    int dl = threadIdx.x & 63;
    int eg = threadIdx.x >> 6;
    int d  = blockIdx.x * 64 + dl;
    int b0 = blockIdx.y * 16;
    int e0 = eg * 64;
    const float* Wp = W + (size_t)e0 * DD + d;
    float acc[16];
    #pragma unroll
    for (int j = 0; j < 16; ++j) acc[j] = 0.f;
    #pragma unroll 8
    for (int e = 0; e < 64; ++e) {
        float w = Wp[(size_t)e * DD];            // wave: 64 contiguous floats
        #pragma unroll
        for (int j = 0; j < 16; ++j)             // h wave-uniform -> scalar loads
            acc[j] = fmaf(h[(size_t)(b0 + j) * DD + e0 + e], w, acc[j]);
    }
    __shared__ float red[16][16][64];            // [eg][b][dl] = 64 KB
    #pragma unroll
    for (int j = 0; j < 16; ++j) red[eg][j][dl] = acc[j];
    __syncthreads();
    // wave eg reduces b0+eg across the 16 e-groups (fixed order, deterministic)
    float s = 0.f;
    #pragma unroll
    for (int g = 0; g < 16; ++g) s += red[g][eg][dl];
    v[(size_t)(b0 + eg) * DD + d] = s;
}

// Kernel B: energies[b,s] = enc[s,b,:] . v[b,:]   (round-3 form, best so far)
// One wave per (b, 16-s chunk); v-row in 16 VGPRs. Main loop has NO cross-lane
// reduce: per-lane partials go to LDS; epilogue reduces 16 rows at once.
__global__ __launch_bounds__(256) void energy_kernel(
    const float* __restrict__ enc, const float* __restrict__ vv, float* __restrict__ e_out) {
    __shared__ float part[4][16][65];    // [wave][row][lane], pad -> 2-way max (free)
    int tid  = threadIdx.x;
    int w    = tid >> 6;
    int lane = tid & 63;
    int wid  = blockIdx.x * 4 + w;
    int b  = wid & (BB - 1);
    int sc = wid >> 6;                   // 0..127
    const float4* vr = (const float4*)(vv + (size_t)b * DD);
    float4 w0 = vr[lane];
    float4 w1 = vr[lane + 64];
    float4 w2 = vr[lane + 128];
    float4 w3 = vr[lane + 192];
    int s0 = sc * 16;
    #pragma unroll 2
    for (int i = 0; i < 16; ++i) {
        const float4* r0 = (const float4*)(enc + ((size_t)(s0 + i) * BB + b) * DD);
        float4 a0 = r0[lane];
        float4 a1 = r0[lane + 64];
        float4 a2 = r0[lane + 128];
        float4 a3 = r0[lane + 192];
        float p = a0.x*w0.x + a0.y*w0.y + a0.z*w0.z + a0.w*w0.w
                + a1.x*w1.x + a1.y*w1.y + a1.z*w1.z + a1.w*w1.w
                + a2.x*w2.x + a2.y*w2.y + a2.z*w2.z + a2.w*w2.w
                + a3.x*w3.x + a3.y*w3.y + a3.z*w3.z + a3.w*w3.w;
        part[w][i][lane] = p;
    }
    __syncthreads();
    // Epilogue: 4 lanes per row; each sums 16 LDS entries, then 2 shfls.
    int r  = lane >> 2;                  // row 0..15
    int qd = lane & 3;                   // quarter
    float sum = 0.f;
    #pragma unroll
    for (int k = 0; k < 16; ++k) sum += part[w][r][qd * 16 + k];
    sum += __shfl_xor(sum, 1, 64);
    sum += __shfl_xor(sum, 2, 64);
    if (qd == 0) e_out[b * SS + s0 + r] = sum;
}

// Kernel C: softmax over s per b. 64 blocks x 256 threads, 8 elems/thread.
__global__ __launch_bounds__(256) void softmax_kernel(
    const float* __restrict__ e_in, float* __restrict__ out) {
    int b   = blockIdx.x;
    int tid = threadIdx.x;
    __shared__ float red[256];
    float vals[8];
    float m = -INFINITY;
    #pragma unroll
    for (int k = 0; k < 8; ++k) {
        vals[k] = e_in[b * SS + tid + 256 * k];
        m = fmaxf(m, vals[k]);
    }
    red[tid] = m;
    __syncthreads();
    for (int off = 128; off > 0; off >>= 1) {
        if (tid < off) red[tid] = fmaxf(red[tid], red[tid + off]);
        __syncthreads();
    }
    m = red[0];
    __syncthreads();
    float sum = 0.f;
    #pragma unroll
    for (int k = 0; k < 8; ++k) {
        vals[k] = expf(vals[k] - m);
        sum += vals[k];
    }
    red[tid] = sum;
    __syncthreads();
    for (int off = 128; off > 0; off >>= 1) {
        if (tid < off) red[tid] += red[tid + off];
        __syncthreads();
    }
    float inv = 1.0f / red[0];
    #pragma unroll
    for (int k = 0; k < 8; ++k)
        out[b * SS + tid + 256 * k] = vals[k] * inv;
}

extern "C" void kernel_launch(void* const* d_in, const int* in_sizes, int n_in,
                              void* d_out, int out_size, void* d_ws, size_t ws_size,
                              hipStream_t stream) {
    const float* hidden = (const float*)d_in[0];   // [1,B,D]
    const float* enc    = (const float*)d_in[1];   // [S,B,D]
    const float* W      = (const float*)d_in[2];   // [D,D]
    // d_in[3] = b_attn: constant per-b shift -> cancels in softmax, unused.
    float* out = (float*)d_out;                    // [B,1,S]

    float* v    = (float*)d_ws;                                      // B*D = 256 KB
    float* e_ws = (float*)((char*)d_ws + BB * DD * sizeof(float));   // B*S = 512 KB

    dim3 gA(DD / 64, BB / 16);
    proj_vec_kernel<<<gA, 1024, 0, stream>>>(hidden, W, v);
    energy_kernel<<<2048, 256, 0, stream>>>(enc, v, e_ws);
    softmax_kernel<<<BB, 256, 0, stream>>>(e_ws, out);
}

// Round 8
// 117.886 us; speedup vs baseline: 1.1916x; 1.1916x over previous
//
#include <hip/hip_runtime.h>
#include <math.h>

#define SS 2048
#define BB 64
#define DD 1024

// Kernel A: v[b][d] = sum_e h[b,e] * W[e,d]   (round-3 form — proven best)
// grid (DD/64, BB/4) = (16,16), block 512 = 8 waves (e-split 8).
__global__ __launch_bounds__(512) void proj_vec_kernel(
    const float* __restrict__ h, const float* __restrict__ W, float* __restrict__ v) {
    int dl = threadIdx.x & 63;
    int eg = threadIdx.x >> 6;
    int d  = blockIdx.x * 64 + dl;
    int b0 = blockIdx.y * 4;
    int e0 = eg * 128;
    const float* h0 = h + (size_t)(b0 + 0) * DD + e0;
    const float* h1 = h + (size_t)(b0 + 1) * DD + e0;
    const float* h2 = h + (size_t)(b0 + 2) * DD + e0;
    const float* h3 = h + (size_t)(b0 + 3) * DD + e0;
    const float* Wp = W + (size_t)e0 * DD + d;
    float a0 = 0.f, a1 = 0.f, a2 = 0.f, a3 = 0.f;
    #pragma unroll 16
    for (int e = 0; e < 128; ++e) {
        float w = Wp[(size_t)e * DD];     // wave: 64 contiguous floats
        a0 = fmaf(h0[e], w, a0);          // h* wave-uniform -> scalar loads
        a1 = fmaf(h1[e], w, a1);
        a2 = fmaf(h2[e], w, a2);
        a3 = fmaf(h3[e], w, a3);
    }
    __shared__ float red[8][4][64];
    red[eg][0][dl] = a0; red[eg][1][dl] = a1;
    red[eg][2][dl] = a2; red[eg][3][dl] = a3;
    __syncthreads();
    if (eg < 4) {   // wave eg reduces b0+eg
        float s = 0.f;
        #pragma unroll
        for (int g = 0; g < 8; ++g) s += red[g][eg][dl];
        v[(size_t)(b0 + eg) * DD + d] = s;
    }
}

// Kernel B: energies[b,s] = enc[s,b,:] . v[b,:]
// 4096 blocks, 8 s-rows per wave (halved block quantum -> scheduler refill,
// smaller tail). Dot computed as 4 independent FMA chains (short critical
// path). Partials -> LDS; epilogue reduce; no in-loop cross-lane ops.
__global__ __launch_bounds__(256) void energy_kernel(
    const float* __restrict__ enc, const float* __restrict__ vv, float* __restrict__ e_out) {
    __shared__ float part[4][8][65];     // [wave][row][lane], pad -> 2-way max (free)
    int tid  = threadIdx.x;
    int w    = tid >> 6;
    int lane = tid & 63;
    int wid  = blockIdx.x * 4 + w;       // 0..16383
    int b  = wid & (BB - 1);
    int sc = wid >> 6;                   // 0..255
    const float4* vr = (const float4*)(vv + (size_t)b * DD);
    float4 w0 = vr[lane];
    float4 w1 = vr[lane + 64];
    float4 w2 = vr[lane + 128];
    float4 w3 = vr[lane + 192];
    int s0 = sc * 8;
    #pragma unroll 2
    for (int i = 0; i < 8; ++i) {
        const float4* r0 = (const float4*)(enc + ((size_t)(s0 + i) * BB + b) * DD);
        float4 a0 = r0[lane];
        float4 a1 = r0[lane + 64];
        float4 a2 = r0[lane + 128];
        float4 a3 = r0[lane + 192];
        float p0 = a0.x*w0.x, p1 = a1.x*w1.x, p2 = a2.x*w2.x, p3 = a3.x*w3.x;
        p0 = fmaf(a0.y, w0.y, p0); p1 = fmaf(a1.y, w1.y, p1);
        p2 = fmaf(a2.y, w2.y, p2); p3 = fmaf(a3.y, w3.y, p3);
        p0 = fmaf(a0.z, w0.z, p0); p1 = fmaf(a1.z, w1.z, p1);
        p2 = fmaf(a2.z, w2.z, p2); p3 = fmaf(a3.z, w3.z, p3);
        p0 = fmaf(a0.w, w0.w, p0); p1 = fmaf(a1.w, w1.w, p1);
        p2 = fmaf(a2.w, w2.w, p2); p3 = fmaf(a3.w, w3.w, p3);
        part[w][i][lane] = (p0 + p1) + (p2 + p3);
    }
    __syncthreads();
    // Epilogue: 8 lanes per row; each sums 8 LDS entries, then 3 shfls.
    int r  = lane >> 3;                  // row 0..7
    int oc = lane & 7;                   // octant
    float sum = 0.f;
    #pragma unroll
    for (int k = 0; k < 8; ++k) sum += part[w][r][oc * 8 + k];
    sum += __shfl_xor(sum, 1, 64);
    sum += __shfl_xor(sum, 2, 64);
    sum += __shfl_xor(sum, 4, 64);
    if (oc == 0) e_out[b * SS + s0 + r] = sum;
}

// Kernel C: softmax over s per b. 64 blocks x 256 threads, 8 elems/thread.
__global__ __launch_bounds__(256) void softmax_kernel(
    const float* __restrict__ e_in, float* __restrict__ out) {
    int b   = blockIdx.x;
    int tid = threadIdx.x;
    __shared__ float red[256];
    float vals[8];
    float m = -INFINITY;
    #pragma unroll
    for (int k = 0; k < 8; ++k) {
        vals[k] = e_in[b * SS + tid + 256 * k];
        m = fmaxf(m, vals[k]);
    }
    red[tid] = m;
    __syncthreads();
    for (int off = 128; off > 0; off >>= 1) {
        if (tid < off) red[tid] = fmaxf(red[tid], red[tid + off]);
        __syncthreads();
    }
    m = red[0];
    __syncthreads();
    float sum = 0.f;
    #pragma unroll
    for (int k = 0; k < 8; ++k) {
        vals[k] = expf(vals[k] - m);
        sum += vals[k];
    }
    red[tid] = sum;
    __syncthreads();
    for (int off = 128; off > 0; off >>= 1) {
        if (tid < off) red[tid] += red[tid + off];
        __syncthreads();
    }
    float inv = 1.0f / red[0];
    #pragma unroll
    for (int k = 0; k < 8; ++k)
        out[b * SS + tid + 256 * k] = vals[k] * inv;
}

extern "C" void kernel_launch(void* const* d_in, const int* in_sizes, int n_in,
                              void* d_out, int out_size, void* d_ws, size_t ws_size,
                              hipStream_t stream) {
    const float* hidden = (const float*)d_in[0];   // [1,B,D]
    const float* enc    = (const float*)d_in[1];   // [S,B,D]
    const float* W      = (const float*)d_in[2];   // [D,D]
    // d_in[3] = b_attn: constant per-b shift -> cancels in softmax, unused.
    float* out = (float*)d_out;                    // [B,1,S]

    float* v    = (float*)d_ws;                                      // B*D = 256 KB
    float* e_ws = (float*)((char*)d_ws + BB * DD * sizeof(float));   // B*S = 512 KB

    dim3 gA(DD / 64, BB / 4);
    proj_vec_kernel<<<gA, 512, 0, stream>>>(hidden, W, v);
    energy_kernel<<<4096, 256, 0, stream>>>(enc, v, e_ws);
    softmax_kernel<<<BB, 256, 0, stream>>>(e_ws, out);
}

// Round 9
// 117.792 us; speedup vs baseline: 1.1926x; 1.0008x over previous
//
#include <hip/hip_runtime.h>
#include <math.h>

#define SS 2048
#define BB 64
#define DD 1024

// Kernel A: v[b][d] = sum_e h[b,e] * W[e,d]   (round-3 form — proven best)
// grid (DD/64, BB/4) = (16,16), block 512 = 8 waves (e-split 8).
__global__ __launch_bounds__(512) void proj_vec_kernel(
    const float* __restrict__ h, const float* __restrict__ W, float* __restrict__ v) {
    int dl = threadIdx.x & 63;
    int eg = threadIdx.x >> 6;
    int d  = blockIdx.x * 64 + dl;
    int b0 = blockIdx.y * 4;
    int e0 = eg * 128;
    const float* h0 = h + (size_t)(b0 + 0) * DD + e0;
    const float* h1 = h + (size_t)(b0 + 1) * DD + e0;
    const float* h2 = h + (size_t)(b0 + 2) * DD + e0;
    const float* h3 = h + (size_t)(b0 + 3) * DD + e0;
    const float* Wp = W + (size_t)e0 * DD + d;
    float a0 = 0.f, a1 = 0.f, a2 = 0.f, a3 = 0.f;
    #pragma unroll 16
    for (int e = 0; e < 128; ++e) {
        float w = Wp[(size_t)e * DD];     // wave: 64 contiguous floats
        a0 = fmaf(h0[e], w, a0);          // h* wave-uniform -> scalar loads
        a1 = fmaf(h1[e], w, a1);
        a2 = fmaf(h2[e], w, a2);
        a3 = fmaf(h3[e], w, a3);
    }
    __shared__ float red[8][4][64];
    red[eg][0][dl] = a0; red[eg][1][dl] = a1;
    red[eg][2][dl] = a2; red[eg][3][dl] = a3;
    __syncthreads();
    if (eg < 4) {   // wave eg reduces b0+eg
        float s = 0.f;
        #pragma unroll
        for (int g = 0; g < 8; ++g) s += red[g][eg][dl];
        v[(size_t)(b0 + eg) * DD + d] = s;
    }
}

// Kernel B: energies[b,s] = enc[s,b,:] . v[b,:]  — slab-streaming layout.
// grid 1024 = (sg 0..255) x (q 0..3); block 1024 thr = 16 waves.
// Wave w owns row b = q*16+w; block collectively reads a 64 KB CONTIGUOUS
// quarter-slab (16 adjacent b-rows) per s-step, 8 s-steps per block.
// ~512 resident blocks -> 4x coarser DRAM granule, 4x fewer streams than
// before. v is 1:1 wave<->b in registers. No __syncthreads in the hot path;
// the partial buffer is wave-private.
__global__ __launch_bounds__(1024) void energy_kernel(
    const float* __restrict__ enc, const float* __restrict__ vv, float* __restrict__ e_out) {
    __shared__ float part[16][8][65];    // 33.3 KB -> 2 blocks/CU
    int tid  = threadIdx.x;
    int w    = tid >> 6;
    int lane = tid & 63;
    int q  = blockIdx.x & 3;
    int sg = blockIdx.x >> 2;            // 0..255
    int b  = q * 16 + w;
    const float4* vr = (const float4*)(vv + (size_t)b * DD);
    float4 w0 = vr[lane];
    float4 w1 = vr[lane + 64];
    float4 w2 = vr[lane + 128];
    float4 w3 = vr[lane + 192];
    int s0 = sg * 8;
    #pragma unroll 2
    for (int i = 0; i < 8; ++i) {
        const float4* r0 = (const float4*)(enc + ((size_t)(s0 + i) * BB + b) * DD);
        float4 a0 = r0[lane];
        float4 a1 = r0[lane + 64];
        float4 a2 = r0[lane + 128];
        float4 a3 = r0[lane + 192];
        float p0 = a0.x*w0.x, p1 = a1.x*w1.x, p2 = a2.x*w2.x, p3 = a3.x*w3.x;
        p0 = fmaf(a0.y, w0.y, p0); p1 = fmaf(a1.y, w1.y, p1);
        p2 = fmaf(a2.y, w2.y, p2); p3 = fmaf(a3.y, w3.y, p3);
        p0 = fmaf(a0.z, w0.z, p0); p1 = fmaf(a1.z, w1.z, p1);
        p2 = fmaf(a2.z, w2.z, p2); p3 = fmaf(a3.z, w3.z, p3);
        p0 = fmaf(a0.w, w0.w, p0); p1 = fmaf(a1.w, w1.w, p1);
        p2 = fmaf(a2.w, w2.w, p2); p3 = fmaf(a3.w, w3.w, p3);
        part[w][i][lane] = (p0 + p1) + (p2 + p3);
    }
    // Wave-private epilogue: 8 lanes per s-row; sum 8 entries, then 3 shfls.
    int r  = lane >> 3;                  // s index 0..7
    int oc = lane & 7;                   // octant
    float sum = 0.f;
    #pragma unroll
    for (int k = 0; k < 8; ++k) sum += part[w][r][oc * 8 + k];
    sum += __shfl_xor(sum, 1, 64);
    sum += __shfl_xor(sum, 2, 64);
    sum += __shfl_xor(sum, 4, 64);
    if (oc == 0) e_out[b * SS + s0 + r] = sum;
}

// Kernel C: softmax over s per b. 64 blocks x 256 threads, 8 elems/thread.
__global__ __launch_bounds__(256) void softmax_kernel(
    const float* __restrict__ e_in, float* __restrict__ out) {
    int b   = blockIdx.x;
    int tid = threadIdx.x;
    __shared__ float red[256];
    float vals[8];
    float m = -INFINITY;
    #pragma unroll
    for (int k = 0; k < 8; ++k) {
        vals[k] = e_in[b * SS + tid + 256 * k];
        m = fmaxf(m, vals[k]);
    }
    red[tid] = m;
    __syncthreads();
    for (int off = 128; off > 0; off >>= 1) {
        if (tid < off) red[tid] = fmaxf(red[tid], red[tid + off]);
        __syncthreads();
    }
    m = red[0];
    __syncthreads();
    float sum = 0.f;
    #pragma unroll
    for (int k = 0; k < 8; ++k) {
        vals[k] = expf(vals[k] - m);
        sum += vals[k];
    }
    red[tid] = sum;
    __syncthreads();
    for (int off = 128; off > 0; off >>= 1) {
        if (tid < off) red[tid] += red[tid + off];
        __syncthreads();
    }
    float inv = 1.0f / red[0];
    #pragma unroll
    for (int k = 0; k < 8; ++k)
        out[b * SS + tid + 256 * k] = vals[k] * inv;
}

extern "C" void kernel_launch(void* const* d_in, const int* in_sizes, int n_in,
                              void* d_out, int out_size, void* d_ws, size_t ws_size,
                              hipStream_t stream) {
    const float* hidden = (const float*)d_in[0];   // [1,B,D]
    const float* enc    = (const float*)d_in[1];   // [S,B,D]
    const float* W      = (const float*)d_in[2];   // [D,D]
    // d_in[3] = b_attn: constant per-b shift -> cancels in softmax, unused.
    float* out = (float*)d_out;                    // [B,1,S]

    float* v    = (float*)d_ws;                                      // B*D = 256 KB
    float* e_ws = (float*)((char*)d_ws + BB * DD * sizeof(float));   // B*S = 512 KB

    dim3 gA(DD / 64, BB / 4);
    proj_vec_kernel<<<gA, 512, 0, stream>>>(hidden, W, v);
    energy_kernel<<<1024, 1024, 0, stream>>>(enc, v, e_ws);
    softmax_kernel<<<BB, 256, 0, stream>>>(e_ws, out);
}